// Round 9
// baseline (266.197 us; speedup 1.0000x reference)
//
#include <hip/hip_runtime.h>
#include <math.h>

#define SROWS 64   // pool rows per block strip
#define PCH   16   // rows per phase
#define QCAP  1024 // k4 compaction queue entries
#define OUTW12 244 // k12 output cols per block (stage = 256)

// ---------------- device helpers ----------------

__device__ __forceinline__ float srgb_to_linear(float x) {
    x = fminf(fmaxf(x, 0.0f), 1.0f);
    return (x <= 0.04045f) ? x * (1.0f / 12.92f)
                           : powf((x + 0.055f) * (1.0f / 1.055f), 2.4f);
}

__device__ __forceinline__ void oklab_ab(float r, float g, float b,
                                         float& A, float& Bc) {
    r = srgb_to_linear(r);
    g = srgb_to_linear(g);
    b = srgb_to_linear(b);
    float l = 0.4122214708f * r + 0.5363325363f * g + 0.0514459929f * b;
    float m = 0.2119034982f * r + 0.6806995451f * g + 0.1073969566f * b;
    float s = 0.0883024619f * r + 0.2817188376f * g + 0.6299787005f * b;
    l = cbrtf(fmaxf(l, 1e-10f));
    m = cbrtf(fmaxf(m, 1e-10f));
    s = cbrtf(fmaxf(s, 1e-10f));
    A  = 1.9779984951f * l - 2.428592205f * m + 0.4505937099f * s;
    Bc = 0.0259040371f * l + 0.7827717662f * m - 0.808675766f  * s;
}

__device__ __forceinline__ void color_terms(const float* __restrict__ pred,
                                            const float* __restrict__ target,
                                            size_t off, size_t HWp, float m,
                                            float& sc, float& sh) {
    float pa, pb, ta, tb;
    oklab_ab(pred[off], pred[off + HWp], pred[off + 2 * HWp], pa, pb);
    oklab_ab(target[off], target[off + HWp], target[off + 2 * HWp], ta, tb);
    float Cp = sqrtf(pa * pa + pb * pb + 1e-12f);
    float Cg = sqrtf(ta * ta + tb * tb + 1e-12f);
    sc += fabsf(Cp - Cg) * m;
    float cosd = (pa * ta + pb * tb) / (Cp * Cg + 1e-12f);
    cosd = fminf(fmaxf(cosd, -1.0f), 1.0f);
    sh += fmaxf(Cg, 0.01f) * (1.0f - cosd) * m;
}

// ---------------- K12: fused sobel edge_soft + 11x11 max-pool ---------------
// Column-strip structure (the measured-fast memory pattern): per-thread scalar
// coalesced loads. Per 16-row phase: stage 28 target rows/channel; sobel done
// separably -- u = vertical [1,2,1], v = vertical [1,0,-1] in registers,
// horizontal neighbors via LDS u/v exchange; e[26] accumulates channel max.
// Then vmax-11 (regs) -> LDS -> hmax-11 -> dil. Writes edge and dil planes.
// Stage col j <-> global col c0-6+j. Outputs: dil cols [c0, c0+244),
// edge cols [c0, c0+244) stored by threads t in [6, 250).

__global__ __launch_bounds__(256) void k12_fused(const float* __restrict__ target,
                                                 float* __restrict__ edge,
                                                 float* __restrict__ dil,
                                                 int H, int W) {
    __shared__ float s_u[26][256];
    __shared__ float s_v[26][256];
    float (*s_dv)[256] = s_u;  // reused after all u/v reads (barrier-protected)

    int cgs = (W + OUTW12 - 1) / OUTW12;   // 5 for W=1024
    int rs  = H / SROWS;                   // 16
    int blk = blockIdx.x;
    int b   = blk / (cgs * rs);
    int rem = blk % (cgs * rs);
    int bxi = rem / rs, ysi = rem % rs;
    int t   = threadIdx.x;
    int c0  = bxi * OUTW12;
    int gcol = c0 - 6 + t;                         // this thread's stage col
    int scc  = min(max(gcol, 0), W - 1);           // clamped address
    bool colok = (gcol >= 0) && (gcol < W);        // sobel zero-pad flag
    size_t HW = (size_t)H * W;
    const float* tb = target + (size_t)b * 3 * HW + scc;
    size_t obase = (size_t)b * HW;
    int ys = ysi * SROWS;
    int tl = max(t - 1, 0), tr = min(t + 1, 255);  // edge threads' e unused

    // col-boundary replicate info (clamped-window semantics for hmax)
    int gc2 = min(max(gcol, 0), W - 1);
    int tc  = gc2 - (c0 - 6);        // stage-local index of clamped col
    bool needfix = (gcol != gc2);

    bool dil_store  = (t < OUTW12) && (c0 + t < W);
    bool edge_store = (t >= 6) && (t < 6 + OUTW12) && (gcol < W);

    for (int ph = 0; ph < SROWS / PCH; ++ph) {
        int f0 = ys + ph * PCH;
        float e[26];
#pragma unroll
        for (int i = 0; i < 26; ++i) e[i] = 0.f;

        for (int c = 0; c < 3; ++c) {
            const float* p = tb + (size_t)c * HW;
            // stage target rows [f0-6, f0+22), zero outside image (sobel pad)
            float w[28];
#pragma unroll
            for (int i = 0; i < 28; ++i) {
                int r  = f0 - 6 + i;
                int rc = min(max(r, 0), H - 1);
                float val = p[(size_t)rc * W];
                w[i] = (colok && r >= 0 && r < H) ? val : 0.f;
            }
            // vertical sobel components for edge rows [f0-5, f0+21)
            float u[26], v[26];
#pragma unroll
            for (int i = 0; i < 26; ++i) {
                u[i] = fmaf(2.f, w[i + 1], w[i]) + w[i + 2];
                v[i] = w[i + 2] - w[i];
            }
            __syncthreads();  // prev readers of s_u/s_v (or prev-phase s_dv) done
#pragma unroll
            for (int i = 0; i < 26; ++i) {
                s_u[i][t] = u[i];
                s_v[i][t] = v[i];
            }
            __syncthreads();
#pragma unroll
            for (int i = 0; i < 26; ++i) {
                float ul = s_u[i][tl], ur = s_u[i][tr];
                float vl = s_v[i][tl], vr = s_v[i][tr];
                float gx = ur - ul;
                float gy = fmaf(2.f, v[i], vl) + vr;
                e[i] = fmaxf(e[i], fabsf(gx) + fabsf(gy));
            }
        }
        // edge_soft = min(2*edge, 1)
#pragma unroll
        for (int i = 0; i < 26; ++i) e[i] = fminf(2.f * e[i], 1.f);
        // vertical clamped-window replicate at image top/bottom
        if (f0 == 0) {              // rows -5..-1 -> row 0 (= e[5])
            e[0] = e[5]; e[1] = e[5]; e[2] = e[5]; e[3] = e[5]; e[4] = e[5];
        }
        if (f0 == H - PCH) {        // rows H..H+4 -> row H-1 (= e[20])
            e[21] = e[20]; e[22] = e[20]; e[23] = e[20]; e[24] = e[20];
            e[25] = e[20];
        }
        // vertical max-11: dv[k] = max(e[k..k+10]), pair-shared
        float dv[16];
#pragma unroll
        for (int m = 0; m < 16; m += 2) {
            float M = e[m + 1];
#pragma unroll
            for (int d = 2; d <= 10; ++d) M = fmaxf(M, e[m + d]);
            dv[m]     = fmaxf(M, e[m]);
            dv[m + 1] = fmaxf(M, e[m + 11]);
        }
        __syncthreads();  // all u/v reads done before overwriting s_u as s_dv
#pragma unroll
        for (int k = 0; k < 16; ++k) s_dv[k][t] = dv[k];
        __syncthreads();
        if (needfix) {    // replicate clamped-col dv (== clamped window)
#pragma unroll
            for (int k = 0; k < 16; ++k) s_dv[k][t] = s_dv[k][tc];
        }
        __syncthreads();
        // horizontal max-11 + dil store; window global [x-5,x+5] = local [t+1,t+11]
        if (dil_store) {
#pragma unroll
            for (int k = 0; k < 16; ++k) {
                float m = s_dv[k][t + 1];
#pragma unroll
                for (int d = 2; d <= 11; ++d) m = fmaxf(m, s_dv[k][t + d]);
                dil[obase + (size_t)(f0 + k) * W + (c0 + t)] = m;
            }
        }
        // edge store (rows [f0, f0+16) = e[5..21), col = gcol)
        if (edge_store) {
#pragma unroll
            for (int k = 0; k < 16; ++k)
                edge[obase + (size_t)(f0 + k) * W + gcol] = e[5 + k];
        }
    }
}

// ---------------- column-strip 2-D pool (vertical in regs, horizontal via LDS) ----

template <int R, bool ISMAX, bool SUB_EDGE>
__global__ __launch_bounds__(256) void pool_kernel(const float* __restrict__ in,
                                                   const float* __restrict__ edge,
                                                   float* __restrict__ out,
                                                   int H, int W) {
    const int OUTW = 256 - 2 * R;
    __shared__ float s_v[PCH][256];
    int cb = (W + OUTW - 1) / OUTW;
    int rs = H / SROWS;
    int blk = blockIdx.x;
    int b   = blk / (cb * rs);
    int t   = blk % (cb * rs);
    int bxi = t / rs, ysi = t % rs;
    int tid = threadIdx.x;
    int col = bxi * OUTW - R + tid;
    int cc  = min(max(col, 0), W - 1);  // replicate == clamped window
    size_t base = (size_t)b * H * W;
    const float* colp = in + base + cc;
    int ys = ysi * SROWS;
    bool writer = (tid >= R) && (tid < OUTW + R) && (col < W);

    for (int ph = 0; ph < SROWS / PCH; ++ph) {
        int y0 = ys + ph * PCH;
        float w[PCH + 2 * R];
#pragma unroll
        for (int k = 0; k < PCH + 2 * R; ++k) {
            int r = min(max(y0 - R + k, 0), H - 1);
            w[k] = colp[(size_t)r * W];
        }
        float v[PCH];
#pragma unroll
        for (int k = 0; k < PCH; ++k) {
            float m = w[k];
#pragma unroll
            for (int d = 1; d <= 2 * R; ++d)
                m = ISMAX ? fmaxf(m, w[k + d]) : fminf(m, w[k + d]);
            v[k] = m;
        }
        __syncthreads();  // previous phase's readers done
#pragma unroll
        for (int k = 0; k < PCH; ++k) s_v[k][tid] = v[k];
        __syncthreads();
        if (writer) {
#pragma unroll
            for (int k = 0; k < PCH; ++k) {
                float m = s_v[k][tid - R];
#pragma unroll
                for (int d = 1; d <= 2 * R; ++d)
                    m = ISMAX ? fmaxf(m, s_v[k][tid - R + d])
                              : fminf(m, s_v[k][tid - R + d]);
                size_t gi = base + (size_t)(y0 + k) * W + col;
                out[gi] = SUB_EDGE ? fmaxf(m - edge[gi], 0.f) : m;
            }
        }
    }
}

// ---------------- K4: 5x5 max-pool + compacted masked OKLab loss ----------------

__global__ __launch_bounds__(256) void k4_loss(const float* __restrict__ pred,
                                               const float* __restrict__ target,
                                               const float* __restrict__ mask0,
                                               float* __restrict__ partials,
                                               int H, int W, int nb) {
    const int R = 2, OUTW = 256 - 2 * R;
    __shared__ float s_v[PCH][256];
    __shared__ int   q_pos[QCAP];
    __shared__ float q_m[QCAP];
    __shared__ int   cnt;
    __shared__ float s_red[3][4];

    int cb = (W + OUTW - 1) / OUTW;
    int rs = H / SROWS;
    int blk = blockIdx.x;
    int b   = blk / (cb * rs);
    int t   = blk % (cb * rs);
    int bxi = t / rs, ysi = t % rs;
    int tid = threadIdx.x;
    int col = bxi * OUTW - R + tid;
    int cc  = min(max(col, 0), W - 1);
    size_t HWp  = (size_t)H * W;
    size_t base = (size_t)b * HWp;
    size_t cbase = (size_t)b * 3 * HWp;
    const float* colp = mask0 + base + cc;
    int ys = ysi * SROWS;
    bool writer = (tid >= R) && (tid < OUTW + R) && (col < W);

    float sm = 0.f, sc = 0.f, sh = 0.f;

    for (int ph = 0; ph < SROWS / PCH; ++ph) {
        int y0 = ys + ph * PCH;
        float w[PCH + 2 * R];
#pragma unroll
        for (int k = 0; k < PCH + 2 * R; ++k) {
            int r = min(max(y0 - R + k, 0), H - 1);
            w[k] = colp[(size_t)r * W];
        }
        float v[PCH];
#pragma unroll
        for (int k = 0; k < PCH; ++k) {
            float m = w[k];
#pragma unroll
            for (int d = 1; d <= 2 * R; ++d) m = fmaxf(m, w[k + d]);
            v[k] = m;
        }
        __syncthreads();  // prev phase queue-processing done
#pragma unroll
        for (int k = 0; k < PCH; ++k) s_v[k][tid] = v[k];
        if (tid == 0) cnt = 0;
        __syncthreads();
        if (writer) {
#pragma unroll
            for (int k = 0; k < PCH; ++k) {
                float m = s_v[k][tid - R];
#pragma unroll
                for (int d = 1; d <= 2 * R; ++d)
                    m = fmaxf(m, s_v[k][tid - R + d]);
                sm += m;
                if (m > 0.f) {
                    int pos = atomicAdd(&cnt, 1);
                    if (pos < QCAP) {
                        q_pos[pos] = ((y0 + k) << 16) | col;
                        q_m[pos] = m;
                    } else {  // overflow fallback (dense mask) — compute inline
                        color_terms(pred, target,
                                    cbase + (size_t)(y0 + k) * W + col,
                                    HWp, m, sc, sh);
                    }
                }
            }
        }
        __syncthreads();
        int n = min(cnt, QCAP);
        for (int i = tid; i < n; i += 256) {
            int pk = q_pos[i];
            color_terms(pred, target,
                        cbase + (size_t)(pk >> 16) * W + (pk & 0xffff),
                        HWp, q_m[i], sc, sh);
        }
    }

    // wave reduce (64 lanes)
#pragma unroll
    for (int off = 32; off > 0; off >>= 1) {
        sm += __shfl_down(sm, off);
        sc += __shfl_down(sc, off);
        sh += __shfl_down(sh, off);
    }
    int lane = tid & 63, wav = tid >> 6;
    __syncthreads();
    if (lane == 0) { s_red[0][wav] = sm; s_red[1][wav] = sc; s_red[2][wav] = sh; }
    __syncthreads();
    if (tid == 0) {
        float tm = 0, tc2 = 0, th = 0;
        for (int i = 0; i < 4; ++i) {
            tm += s_red[0][i]; tc2 += s_red[1][i]; th += s_red[2][i];
        }
        partials[blk]          = tm;
        partials[nb + blk]     = tc2;
        partials[2 * nb + blk] = th;
    }
}

__global__ void finalize_kernel(const float* __restrict__ partials, int nb,
                                float* __restrict__ out) {
    double sm = 0.0, sc = 0.0, sh = 0.0;
    for (int i = threadIdx.x; i < nb; i += blockDim.x) {
        sm += (double)partials[i];
        sc += (double)partials[nb + i];
        sh += (double)partials[2 * nb + i];
    }
    __shared__ double red[3][256];
    red[0][threadIdx.x] = sm;
    red[1][threadIdx.x] = sc;
    red[2][threadIdx.x] = sh;
    __syncthreads();
    for (int s = blockDim.x / 2; s > 0; s >>= 1) {
        if ((int)threadIdx.x < s) {
            red[0][threadIdx.x] += red[0][threadIdx.x + s];
            red[1][threadIdx.x] += red[1][threadIdx.x + s];
            red[2][threadIdx.x] += red[2][threadIdx.x + s];
        }
        __syncthreads();
    }
    if (threadIdx.x == 0) {
        double ms = fmax(red[0][0], 1.0);
        out[0] = (float)(red[1][0] / ms + 2.0 * red[2][0] / ms);
    }
}

// ---------------- host launch ----------------

extern "C" void kernel_launch(void* const* d_in, const int* in_sizes, int n_in,
                              void* d_out, int out_size, void* d_ws, size_t ws_size,
                              hipStream_t stream) {
    const float* pred   = (const float*)d_in[0];
    const float* target = (const float*)d_in[1];
    float* out = (float*)d_out;

    const int H = 1024, W = 1024;  // fixed problem shape
    int Bn = in_sizes[0] / (3 * H * W);
    size_t plane = (size_t)Bn * H * W * sizeof(float);

    char* ws = (char*)d_ws;
    float* planeA = (float*)ws;            // edge, then mask0 (in place)
    float* planeB = (float*)(ws + plane);  // dilated
    float* partials = (float*)(ws + 2 * plane);

    int rs  = H / SROWS;                        // 16
    int cgs = (W + OUTW12 - 1) / OUTW12;        // 5
    int g12 = Bn * cgs * rs;                    // 640
    int cbP = (W + 245) / 246;                  // 5
    int cb4 = (W + 251) / 252;                  // 5
    int gP = Bn * cbP * rs;
    int g4 = Bn * cb4 * rs;

    // 1+2. fused sobel edge_soft + 11x11 max-pool -> planeA (edge), planeB (dil)
    k12_fused<<<g12, 256, 0, stream>>>(target, planeA, planeB, H, W);
    // 3. 11x11 min-pool + relu(closed - edge) -> planeA in place (mask0)
    pool_kernel<5, false, true><<<gP, 256, 0, stream>>>(planeB, planeA, planeA, H, W);
    // 4. 5x5 max-pool + compacted masked loss -> partials
    k4_loss<<<g4, 256, 0, stream>>>(pred, target, planeA, partials, H, W, g4);
    // 5. final reduce + combine
    finalize_kernel<<<1, 256, 0, stream>>>(partials, g4, out);
}

// Round 10
// 145.572 us; speedup vs baseline: 1.8286x; 1.8286x over previous
//
#include <hip/hip_runtime.h>
#include <math.h>

#define SROWS 64     // pool rows per block strip
#define PCH   16     // pool rows per LDS phase
#define QCAP  1024   // k4 compaction queue entries
#define K1_PCH  16   // k1 rows per phase
#define K1_SROWS 32  // k1 rows per block strip
#define K1_OUTW 254  // k1 output cols per block (stage 256)

// ---------------- device helpers ----------------

__device__ __forceinline__ float srgb_to_linear(float x) {
    x = fminf(fmaxf(x, 0.0f), 1.0f);
    return (x <= 0.04045f) ? x * (1.0f / 12.92f)
                           : powf((x + 0.055f) * (1.0f / 1.055f), 2.4f);
}

__device__ __forceinline__ void oklab_ab(float r, float g, float b,
                                         float& A, float& Bc) {
    r = srgb_to_linear(r);
    g = srgb_to_linear(g);
    b = srgb_to_linear(b);
    float l = 0.4122214708f * r + 0.5363325363f * g + 0.0514459929f * b;
    float m = 0.2119034982f * r + 0.6806995451f * g + 0.1073969566f * b;
    float s = 0.0883024619f * r + 0.2817188376f * g + 0.6299787005f * b;
    l = cbrtf(fmaxf(l, 1e-10f));
    m = cbrtf(fmaxf(m, 1e-10f));
    s = cbrtf(fmaxf(s, 1e-10f));
    A  = 1.9779984951f * l - 2.428592205f * m + 0.4505937099f * s;
    Bc = 0.0259040371f * l + 0.7827717662f * m - 0.808675766f  * s;
}

__device__ __forceinline__ void color_terms(const float* __restrict__ pred,
                                            const float* __restrict__ target,
                                            size_t off, size_t HWp, float m,
                                            float& sc, float& sh) {
    float pa, pb, ta, tb;
    oklab_ab(pred[off], pred[off + HWp], pred[off + 2 * HWp], pa, pb);
    oklab_ab(target[off], target[off + HWp], target[off + 2 * HWp], ta, tb);
    float Cp = sqrtf(pa * pa + pb * pb + 1e-12f);
    float Cg = sqrtf(ta * ta + tb * tb + 1e-12f);
    sc += fabsf(Cp - Cg) * m;
    float cosd = (pa * ta + pb * tb) / (Cp * Cg + 1e-12f);
    cosd = fminf(fmaxf(cosd, -1.0f), 1.0f);
    sh += fmaxf(Cg, 0.01f) * (1.0f - cosd) * m;
}

// ---------------- K1: sobel edge_soft in the pool skeleton -----------------
// Column-strip, per-thread scalar column loads: 18 independent loads per
// channel issued up front (Little's-law concurrency like the pool kernels).
// Horizontal sobel via LDS exchange of vertical components u,v.
// Small working set: w[18] + e[16] => ~48 VGPR; LDS 32 KB => 5 blocks/CU.

__global__ __launch_bounds__(256) void k1_edge(const float* __restrict__ target,
                                               float* __restrict__ edge,
                                               int H, int W) {
    __shared__ float s_u[K1_PCH][256];
    __shared__ float s_v[K1_PCH][256];

    int cb  = (W + K1_OUTW - 1) / K1_OUTW;   // 5
    int rs  = H / K1_SROWS;                  // 32
    int blk = blockIdx.x;
    int b   = blk / (cb * rs);
    int rem = blk % (cb * rs);
    int bxi = rem / rs, ysi = rem % rs;
    int t   = threadIdx.x;
    int c0  = bxi * K1_OUTW;
    int gcol = c0 - 1 + t;                   // staged col
    int scc  = min(max(gcol, 0), W - 1);
    bool colok = (gcol >= 0) && (gcol < W);  // zero-pad outside image
    size_t HW = (size_t)H * W;
    const float* tb = target + (size_t)b * 3 * HW + scc;
    float* ep = edge + (size_t)b * HW;
    int ys = ysi * K1_SROWS;
    bool writer = (t >= 1) && (t < 1 + K1_OUTW) && (gcol < W);
    int tl = max(t - 1, 0), tr = min(t + 1, 255);  // border threads unused

    for (int ph = 0; ph < K1_SROWS / K1_PCH; ++ph) {
        int f0 = ys + ph * K1_PCH;
        float e[K1_PCH];
#pragma unroll
        for (int i = 0; i < K1_PCH; ++i) e[i] = 0.f;

        for (int c = 0; c < 3; ++c) {
            const float* p = tb + (size_t)c * HW;
            // 18 independent scalar loads, all issued before any use
            float w[K1_PCH + 2];
#pragma unroll
            for (int i = 0; i < K1_PCH + 2; ++i) {
                int r  = f0 - 1 + i;
                int rc = min(max(r, 0), H - 1);
                float val = p[(size_t)rc * W];
                w[i] = (colok && r >= 0 && r < H) ? val : 0.f;
            }
            __syncthreads();  // prev channel's (or phase's) LDS reads done
#pragma unroll
            for (int i = 0; i < K1_PCH; ++i) {
                s_u[i][t] = fmaf(2.f, w[i + 1], w[i]) + w[i + 2];
                s_v[i][t] = w[i + 2] - w[i];
            }
            __syncthreads();
#pragma unroll
            for (int i = 0; i < K1_PCH; ++i) {
                float vc = w[i + 2] - w[i];                 // center v (reg)
                float gx = s_u[i][tr] - s_u[i][tl];
                float gy = fmaf(2.f, vc, s_v[i][tl]) + s_v[i][tr];
                e[i] = fmaxf(e[i], fabsf(gx) + fabsf(gy));
            }
        }
        if (writer) {
#pragma unroll
            for (int i = 0; i < K1_PCH; ++i)
                ep[(size_t)(f0 + i) * W + gcol] = fminf(2.f * e[i], 1.f);
        }
    }
}

// ---------------- column-strip 2-D pool (vertical in regs, horizontal via LDS) ----

template <int R, bool ISMAX, bool SUB_EDGE>
__global__ __launch_bounds__(256) void pool_kernel(const float* __restrict__ in,
                                                   const float* __restrict__ edge,
                                                   float* __restrict__ out,
                                                   int H, int W) {
    const int OUTW = 256 - 2 * R;
    __shared__ float s_v[PCH][256];
    int cb = (W + OUTW - 1) / OUTW;
    int rs = H / SROWS;
    int blk = blockIdx.x;
    int b   = blk / (cb * rs);
    int t   = blk % (cb * rs);
    int bxi = t / rs, ysi = t % rs;
    int tid = threadIdx.x;
    int col = bxi * OUTW - R + tid;
    int cc  = min(max(col, 0), W - 1);  // replicate == clamped window
    size_t base = (size_t)b * H * W;
    const float* colp = in + base + cc;
    int ys = ysi * SROWS;
    bool writer = (tid >= R) && (tid < OUTW + R) && (col < W);

    for (int ph = 0; ph < SROWS / PCH; ++ph) {
        int y0 = ys + ph * PCH;
        float w[PCH + 2 * R];
#pragma unroll
        for (int k = 0; k < PCH + 2 * R; ++k) {
            int r = min(max(y0 - R + k, 0), H - 1);
            w[k] = colp[(size_t)r * W];
        }
        float v[PCH];
#pragma unroll
        for (int k = 0; k < PCH; ++k) {
            float m = w[k];
#pragma unroll
            for (int d = 1; d <= 2 * R; ++d)
                m = ISMAX ? fmaxf(m, w[k + d]) : fminf(m, w[k + d]);
            v[k] = m;
        }
        __syncthreads();  // previous phase's readers done
#pragma unroll
        for (int k = 0; k < PCH; ++k) s_v[k][tid] = v[k];
        __syncthreads();
        if (writer) {
#pragma unroll
            for (int k = 0; k < PCH; ++k) {
                float m = s_v[k][tid - R];
#pragma unroll
                for (int d = 1; d <= 2 * R; ++d)
                    m = ISMAX ? fmaxf(m, s_v[k][tid - R + d])
                              : fminf(m, s_v[k][tid - R + d]);
                size_t gi = base + (size_t)(y0 + k) * W + col;
                out[gi] = SUB_EDGE ? fmaxf(m - edge[gi], 0.f) : m;
            }
        }
    }
}

// ---------------- K4: 5x5 max-pool + compacted masked OKLab loss ----------------

__global__ __launch_bounds__(256) void k4_loss(const float* __restrict__ pred,
                                               const float* __restrict__ target,
                                               const float* __restrict__ mask0,
                                               float* __restrict__ partials,
                                               int H, int W, int nb) {
    const int R = 2, OUTW = 256 - 2 * R;
    __shared__ float s_v[PCH][256];
    __shared__ int   q_pos[QCAP];
    __shared__ float q_m[QCAP];
    __shared__ int   cnt;
    __shared__ float s_red[3][4];

    int cb = (W + OUTW - 1) / OUTW;
    int rs = H / SROWS;
    int blk = blockIdx.x;
    int b   = blk / (cb * rs);
    int t   = blk % (cb * rs);
    int bxi = t / rs, ysi = t % rs;
    int tid = threadIdx.x;
    int col = bxi * OUTW - R + tid;
    int cc  = min(max(col, 0), W - 1);
    size_t HWp  = (size_t)H * W;
    size_t base = (size_t)b * HWp;
    size_t cbase = (size_t)b * 3 * HWp;
    const float* colp = mask0 + base + cc;
    int ys = ysi * SROWS;
    bool writer = (tid >= R) && (tid < OUTW + R) && (col < W);

    float sm = 0.f, sc = 0.f, sh = 0.f;

    for (int ph = 0; ph < SROWS / PCH; ++ph) {
        int y0 = ys + ph * PCH;
        float w[PCH + 2 * R];
#pragma unroll
        for (int k = 0; k < PCH + 2 * R; ++k) {
            int r = min(max(y0 - R + k, 0), H - 1);
            w[k] = colp[(size_t)r * W];
        }
        float v[PCH];
#pragma unroll
        for (int k = 0; k < PCH; ++k) {
            float m = w[k];
#pragma unroll
            for (int d = 1; d <= 2 * R; ++d) m = fmaxf(m, w[k + d]);
            v[k] = m;
        }
        __syncthreads();  // prev phase queue-processing done
#pragma unroll
        for (int k = 0; k < PCH; ++k) s_v[k][tid] = v[k];
        if (tid == 0) cnt = 0;
        __syncthreads();
        if (writer) {
#pragma unroll
            for (int k = 0; k < PCH; ++k) {
                float m = s_v[k][tid - R];
#pragma unroll
                for (int d = 1; d <= 2 * R; ++d)
                    m = fmaxf(m, s_v[k][tid - R + d]);
                sm += m;
                if (m > 0.f) {
                    int pos = atomicAdd(&cnt, 1);
                    if (pos < QCAP) {
                        q_pos[pos] = ((y0 + k) << 16) | col;
                        q_m[pos] = m;
                    } else {  // overflow fallback (dense mask) — compute inline
                        color_terms(pred, target,
                                    cbase + (size_t)(y0 + k) * W + col,
                                    HWp, m, sc, sh);
                    }
                }
            }
        }
        __syncthreads();
        int n = min(cnt, QCAP);
        for (int i = tid; i < n; i += 256) {
            int pk = q_pos[i];
            color_terms(pred, target,
                        cbase + (size_t)(pk >> 16) * W + (pk & 0xffff),
                        HWp, q_m[i], sc, sh);
        }
    }

    // wave reduce (64 lanes)
#pragma unroll
    for (int off = 32; off > 0; off >>= 1) {
        sm += __shfl_down(sm, off);
        sc += __shfl_down(sc, off);
        sh += __shfl_down(sh, off);
    }
    int lane = tid & 63, wav = tid >> 6;
    __syncthreads();
    if (lane == 0) { s_red[0][wav] = sm; s_red[1][wav] = sc; s_red[2][wav] = sh; }
    __syncthreads();
    if (tid == 0) {
        float tm = 0, tc = 0, th = 0;
        for (int i = 0; i < 4; ++i) {
            tm += s_red[0][i]; tc += s_red[1][i]; th += s_red[2][i];
        }
        partials[blk]          = tm;
        partials[nb + blk]     = tc;
        partials[2 * nb + blk] = th;
    }
}

__global__ void finalize_kernel(const float* __restrict__ partials, int nb,
                                float* __restrict__ out) {
    double sm = 0.0, sc = 0.0, sh = 0.0;
    for (int i = threadIdx.x; i < nb; i += blockDim.x) {
        sm += (double)partials[i];
        sc += (double)partials[nb + i];
        sh += (double)partials[2 * nb + i];
    }
    __shared__ double red[3][256];
    red[0][threadIdx.x] = sm;
    red[1][threadIdx.x] = sc;
    red[2][threadIdx.x] = sh;
    __syncthreads();
    for (int s = blockDim.x / 2; s > 0; s >>= 1) {
        if ((int)threadIdx.x < s) {
            red[0][threadIdx.x] += red[0][threadIdx.x + s];
            red[1][threadIdx.x] += red[1][threadIdx.x + s];
            red[2][threadIdx.x] += red[2][threadIdx.x + s];
        }
        __syncthreads();
    }
    if (threadIdx.x == 0) {
        double ms = fmax(red[0][0], 1.0);
        out[0] = (float)(red[1][0] / ms + 2.0 * red[2][0] / ms);
    }
}

// ---------------- host launch ----------------

extern "C" void kernel_launch(void* const* d_in, const int* in_sizes, int n_in,
                              void* d_out, int out_size, void* d_ws, size_t ws_size,
                              hipStream_t stream) {
    const float* pred   = (const float*)d_in[0];
    const float* target = (const float*)d_in[1];
    float* out = (float*)d_out;

    const int H = 1024, W = 1024;  // fixed problem shape
    int Bn = in_sizes[0] / (3 * H * W);
    size_t plane = (size_t)Bn * H * W * sizeof(float);

    char* ws = (char*)d_ws;
    float* planeA = (float*)ws;            // edge, then mask0 (in place)
    float* planeB = (float*)(ws + plane);  // dilated
    float* partials = (float*)(ws + 2 * plane);

    int rs1 = H / K1_SROWS;                    // 32
    int cb1 = (W + K1_OUTW - 1) / K1_OUTW;     // 5
    int g1  = Bn * cb1 * rs1;                  // 1280
    int rs  = H / SROWS;                       // 16
    int cbP = (W + 245) / 246;                 // 5
    int cb4 = (W + 251) / 252;                 // 5
    int gP = Bn * cbP * rs;
    int g4 = Bn * cb4 * rs;

    // 1. sobel edge_soft -> planeA  (pool-skeleton, high load concurrency)
    k1_edge<<<g1, 256, 0, stream>>>(target, planeA, H, W);
    // 2. 11x11 max-pool -> planeB (dilated)
    pool_kernel<5, true, false><<<gP, 256, 0, stream>>>(planeA, nullptr, planeB, H, W);
    // 3. 11x11 min-pool + relu(closed - edge) -> planeA in place (mask0)
    pool_kernel<5, false, true><<<gP, 256, 0, stream>>>(planeB, planeA, planeA, H, W);
    // 4. 5x5 max-pool + compacted masked loss -> partials
    k4_loss<<<g4, 256, 0, stream>>>(pred, target, planeA, partials, H, W, g4);
    // 5. final reduce + combine
    finalize_kernel<<<1, 256, 0, stream>>>(partials, g4, out);
}

// Round 11
// 100.966 us; speedup vs baseline: 2.6365x; 1.4418x over previous
//
#include <hip/hip_runtime.h>
#include <math.h>

#define K1_NR 16   // k1 rows per strip
#define SROWS 64   // pool rows per block strip
#define PCH   16   // pool rows per LDS phase
#define QCAP  1024 // k4 compaction queue entries

// ---------------- device helpers ----------------

__device__ __forceinline__ float srgb_to_linear(float x) {
    x = fminf(fmaxf(x, 0.0f), 1.0f);
    return (x <= 0.04045f) ? x * (1.0f / 12.92f)
                           : powf((x + 0.055f) * (1.0f / 1.055f), 2.4f);
}

__device__ __forceinline__ void oklab_ab(float r, float g, float b,
                                         float& A, float& Bc) {
    r = srgb_to_linear(r);
    g = srgb_to_linear(g);
    b = srgb_to_linear(b);
    float l = 0.4122214708f * r + 0.5363325363f * g + 0.0514459929f * b;
    float m = 0.2119034982f * r + 0.6806995451f * g + 0.1073969566f * b;
    float s = 0.0883024619f * r + 0.2817188376f * g + 0.6299787005f * b;
    l = cbrtf(fmaxf(l, 1e-10f));
    m = cbrtf(fmaxf(m, 1e-10f));
    s = cbrtf(fmaxf(s, 1e-10f));
    A  = 1.9779984951f * l - 2.428592205f * m + 0.4505937099f * s;
    Bc = 0.0259040371f * l + 0.7827717662f * m - 0.808675766f  * s;
}

__device__ __forceinline__ void color_terms(const float* __restrict__ pred,
                                            const float* __restrict__ target,
                                            size_t off, size_t HWp, float m,
                                            float& sc, float& sh) {
    float pa, pb, ta, tb;
    oklab_ab(pred[off], pred[off + HWp], pred[off + 2 * HWp], pa, pb);
    oklab_ab(target[off], target[off + HWp], target[off + 2 * HWp], ta, tb);
    float Cp = sqrtf(pa * pa + pb * pb + 1e-12f);
    float Cg = sqrtf(ta * ta + tb * tb + 1e-12f);
    sc += fabsf(Cp - Cg) * m;
    float cosd = (pa * ta + pb * tb) / (Cp * Cg + 1e-12f);
    cosd = fminf(fmaxf(cosd, -1.0f), 1.0f);
    sh += fmaxf(Cg, 0.01f) * (1.0f - cosd) * m;
}

// ---------------- K1: sobel edge_soft, channel-staggered rows ---------------
// Round-7 skeleton (float4 lanes, rolling rows, scalar halos, no LDS), but
// the three channel pipelines are staggered by one row: at iteration s the
// wave loads ch0 row s+1, ch1 row s, ch2 row s-1. Simultaneous per-wave
// addresses differ by 4MiB +/- 4KiB -> distinct DRAM rows/banks (the 4MiB
// channel-plane separation aliases to the same bank when rows are equal —
// the measured peak/3 ceiling of rounds 3/7/8). Channel max is completed
// via a 2-deep accumulator ring; row s-2 is written after ch2 contributes.

__device__ __forceinline__ void k1_load_row(const float* __restrict__ tb,
                                            size_t HW, int c, int r,
                                            int H, int W, int col0,
                                            bool lok, bool rok, int lc, int rc,
                                            float4& m4, float& ml, float& mr) {
    if (r >= 0 && r < H) {
        const float* rp = tb + (size_t)c * HW + (size_t)r * W;
        m4 = *(const float4*)(rp + col0);
        ml = lok ? rp[lc] : 0.f;
        mr = rok ? rp[rc] : 0.f;
    } else {  // sobel zero-pad
        m4 = make_float4(0.f, 0.f, 0.f, 0.f);
        ml = 0.f; mr = 0.f;
    }
}

__device__ __forceinline__ float4 k1_sobel_g(const float4& pr, const float4& cu,
                                             const float4& nx,
                                             float lpr, float lcu, float lnx,
                                             float rpr, float rcu, float rnx) {
    float4 u, v;
    u.x = fmaf(2.f, cu.x, pr.x) + nx.x;
    u.y = fmaf(2.f, cu.y, pr.y) + nx.y;
    u.z = fmaf(2.f, cu.z, pr.z) + nx.z;
    u.w = fmaf(2.f, cu.w, pr.w) + nx.w;
    v.x = nx.x - pr.x; v.y = nx.y - pr.y;
    v.z = nx.z - pr.z; v.w = nx.w - pr.w;
    float ul = fmaf(2.f, lcu, lpr) + lnx;
    float vl = lnx - lpr;
    float ur = fmaf(2.f, rcu, rpr) + rnx;
    float vr = rnx - rpr;
    float4 g;
    g.x = fabsf(u.y - ul)  + fabsf(fmaf(2.f, v.x, vl) + v.y);
    g.y = fabsf(u.z - u.x) + fabsf(fmaf(2.f, v.y, v.x) + v.z);
    g.z = fabsf(u.w - u.y) + fabsf(fmaf(2.f, v.z, v.y) + v.w);
    g.w = fabsf(ur - u.z)  + fabsf(fmaf(2.f, v.w, v.z) + vr);
    return g;
}

__global__ __launch_bounds__(256) void k1_edge(const float* __restrict__ target,
                                               float* __restrict__ edge,
                                               int H, int W) {
    int strips = H / K1_NR;
    int b   = blockIdx.x / strips;
    int ysi = blockIdx.x % strips;
    int t   = threadIdx.x;
    int col0 = t << 2;                    // 256 threads x 4 cols = W
    int y0 = ysi * K1_NR;
    int yend = y0 + K1_NR - 1;
    size_t HW = (size_t)H * W;
    const float* tb = target + (size_t)b * 3 * HW;
    float* ep = edge + (size_t)b * HW + col0;

    bool lok = (col0 > 0);
    bool rok = (col0 + 4 < W);
    int lc = lok ? col0 - 1 : 0;
    int rc = rok ? col0 + 4 : W - 1;

    // channel c computes g_c(s-c) at iteration s; state rows (s-c-1, s-c)
    float4 pr[3], cu[3];
    float lpr[3], lcu[3], rpr[3], rcu[3];
#pragma unroll
    for (int c = 0; c < 3; ++c) {
        k1_load_row(tb, HW, c, y0 - c - 1, H, W, col0, lok, rok, lc, rc,
                    pr[c], lpr[c], rpr[c]);
        k1_load_row(tb, HW, c, y0 - c, H, W, col0, lok, rok, lc, rc,
                    cu[c], lcu[c], rcu[c]);
    }

    float4 acc1 = make_float4(0.f, 0.f, 0.f, 0.f);  // partial for row s-1
    float4 acc2 = make_float4(0.f, 0.f, 0.f, 0.f);  // partial for row s-2

    for (int s = y0; s < y0 + K1_NR + 2; ++s) {
        float4 g0 = make_float4(0.f, 0.f, 0.f, 0.f);
#pragma unroll
        for (int c = 0; c < 3; ++c) {
            if (s - c <= yend) {            // wave-uniform gate
                float4 nx; float lnx, rnx;
                k1_load_row(tb, HW, c, s - c + 1, H, W, col0, lok, rok, lc, rc,
                            nx, lnx, rnx);
                float4 g = k1_sobel_g(pr[c], cu[c], nx,
                                      lpr[c], lcu[c], lnx,
                                      rpr[c], rcu[c], rnx);
                if (c == 0) {
                    g0 = g;
                } else if (c == 1) {
                    acc1.x = fmaxf(acc1.x, g.x); acc1.y = fmaxf(acc1.y, g.y);
                    acc1.z = fmaxf(acc1.z, g.z); acc1.w = fmaxf(acc1.w, g.w);
                } else {
                    acc2.x = fmaxf(acc2.x, g.x); acc2.y = fmaxf(acc2.y, g.y);
                    acc2.z = fmaxf(acc2.z, g.z); acc2.w = fmaxf(acc2.w, g.w);
                }
                pr[c] = cu[c]; cu[c] = nx;
                lpr[c] = lcu[c]; lcu[c] = lnx;
                rpr[c] = rcu[c]; rcu[c] = rnx;
            }
        }
        if (s >= y0 + 2) {                  // row s-2 complete: write
            float4 e;
            e.x = fminf(2.f * acc2.x, 1.f);
            e.y = fminf(2.f * acc2.y, 1.f);
            e.z = fminf(2.f * acc2.z, 1.f);
            e.w = fminf(2.f * acc2.w, 1.f);
            *(float4*)(ep + (size_t)(s - 2) * W) = e;
        }
        acc2 = acc1;
        acc1 = g0;
    }
}

// ---------------- column-strip 2-D pool (vertical in regs, horizontal via LDS) ----

template <int R, bool ISMAX, bool SUB_EDGE>
__global__ __launch_bounds__(256) void pool_kernel(const float* __restrict__ in,
                                                   const float* __restrict__ edge,
                                                   float* __restrict__ out,
                                                   int H, int W) {
    const int OUTW = 256 - 2 * R;
    __shared__ float s_v[PCH][256];
    int cb = (W + OUTW - 1) / OUTW;
    int rs = H / SROWS;
    int blk = blockIdx.x;
    int b   = blk / (cb * rs);
    int t   = blk % (cb * rs);
    int bxi = t / rs, ysi = t % rs;
    int tid = threadIdx.x;
    int col = bxi * OUTW - R + tid;
    int cc  = min(max(col, 0), W - 1);  // replicate == clamped window
    size_t base = (size_t)b * H * W;
    const float* colp = in + base + cc;
    int ys = ysi * SROWS;
    bool writer = (tid >= R) && (tid < OUTW + R) && (col < W);

    for (int ph = 0; ph < SROWS / PCH; ++ph) {
        int y0 = ys + ph * PCH;
        float w[PCH + 2 * R];
#pragma unroll
        for (int k = 0; k < PCH + 2 * R; ++k) {
            int r = min(max(y0 - R + k, 0), H - 1);
            w[k] = colp[(size_t)r * W];
        }
        float v[PCH];
#pragma unroll
        for (int k = 0; k < PCH; ++k) {
            float m = w[k];
#pragma unroll
            for (int d = 1; d <= 2 * R; ++d)
                m = ISMAX ? fmaxf(m, w[k + d]) : fminf(m, w[k + d]);
            v[k] = m;
        }
        __syncthreads();  // previous phase's readers done
#pragma unroll
        for (int k = 0; k < PCH; ++k) s_v[k][tid] = v[k];
        __syncthreads();
        if (writer) {
#pragma unroll
            for (int k = 0; k < PCH; ++k) {
                float m = s_v[k][tid - R];
#pragma unroll
                for (int d = 1; d <= 2 * R; ++d)
                    m = ISMAX ? fmaxf(m, s_v[k][tid - R + d])
                              : fminf(m, s_v[k][tid - R + d]);
                size_t gi = base + (size_t)(y0 + k) * W + col;
                out[gi] = SUB_EDGE ? fmaxf(m - edge[gi], 0.f) : m;
            }
        }
    }
}

// ---------------- K4: 5x5 max-pool + compacted masked OKLab loss ----------------

__global__ __launch_bounds__(256) void k4_loss(const float* __restrict__ pred,
                                               const float* __restrict__ target,
                                               const float* __restrict__ mask0,
                                               float* __restrict__ partials,
                                               int H, int W, int nb) {
    const int R = 2, OUTW = 256 - 2 * R;
    __shared__ float s_v[PCH][256];
    __shared__ int   q_pos[QCAP];
    __shared__ float q_m[QCAP];
    __shared__ int   cnt;
    __shared__ float s_red[3][4];

    int cb = (W + OUTW - 1) / OUTW;
    int rs = H / SROWS;
    int blk = blockIdx.x;
    int b   = blk / (cb * rs);
    int t   = blk % (cb * rs);
    int bxi = t / rs, ysi = t % rs;
    int tid = threadIdx.x;
    int col = bxi * OUTW - R + tid;
    int cc  = min(max(col, 0), W - 1);
    size_t HWp  = (size_t)H * W;
    size_t base = (size_t)b * HWp;
    size_t cbase = (size_t)b * 3 * HWp;
    const float* colp = mask0 + base + cc;
    int ys = ysi * SROWS;
    bool writer = (tid >= R) && (tid < OUTW + R) && (col < W);

    float sm = 0.f, sc = 0.f, sh = 0.f;

    for (int ph = 0; ph < SROWS / PCH; ++ph) {
        int y0 = ys + ph * PCH;
        float w[PCH + 2 * R];
#pragma unroll
        for (int k = 0; k < PCH + 2 * R; ++k) {
            int r = min(max(y0 - R + k, 0), H - 1);
            w[k] = colp[(size_t)r * W];
        }
        float v[PCH];
#pragma unroll
        for (int k = 0; k < PCH; ++k) {
            float m = w[k];
#pragma unroll
            for (int d = 1; d <= 2 * R; ++d) m = fmaxf(m, w[k + d]);
            v[k] = m;
        }
        __syncthreads();  // prev phase queue-processing done
#pragma unroll
        for (int k = 0; k < PCH; ++k) s_v[k][tid] = v[k];
        if (tid == 0) cnt = 0;
        __syncthreads();
        if (writer) {
#pragma unroll
            for (int k = 0; k < PCH; ++k) {
                float m = s_v[k][tid - R];
#pragma unroll
                for (int d = 1; d <= 2 * R; ++d)
                    m = fmaxf(m, s_v[k][tid - R + d]);
                sm += m;
                if (m > 0.f) {
                    int pos = atomicAdd(&cnt, 1);
                    if (pos < QCAP) {
                        q_pos[pos] = ((y0 + k) << 16) | col;
                        q_m[pos] = m;
                    } else {  // overflow fallback (dense mask) — compute inline
                        color_terms(pred, target,
                                    cbase + (size_t)(y0 + k) * W + col,
                                    HWp, m, sc, sh);
                    }
                }
            }
        }
        __syncthreads();
        int n = min(cnt, QCAP);
        for (int i = tid; i < n; i += 256) {
            int pk = q_pos[i];
            color_terms(pred, target,
                        cbase + (size_t)(pk >> 16) * W + (pk & 0xffff),
                        HWp, q_m[i], sc, sh);
        }
    }

    // wave reduce (64 lanes)
#pragma unroll
    for (int off = 32; off > 0; off >>= 1) {
        sm += __shfl_down(sm, off);
        sc += __shfl_down(sc, off);
        sh += __shfl_down(sh, off);
    }
    int lane = tid & 63, wav = tid >> 6;
    __syncthreads();
    if (lane == 0) { s_red[0][wav] = sm; s_red[1][wav] = sc; s_red[2][wav] = sh; }
    __syncthreads();
    if (tid == 0) {
        float tm = 0, tc = 0, th = 0;
        for (int i = 0; i < 4; ++i) {
            tm += s_red[0][i]; tc += s_red[1][i]; th += s_red[2][i];
        }
        partials[blk]          = tm;
        partials[nb + blk]     = tc;
        partials[2 * nb + blk] = th;
    }
}

__global__ void finalize_kernel(const float* __restrict__ partials, int nb,
                                float* __restrict__ out) {
    double sm = 0.0, sc = 0.0, sh = 0.0;
    for (int i = threadIdx.x; i < nb; i += blockDim.x) {
        sm += (double)partials[i];
        sc += (double)partials[nb + i];
        sh += (double)partials[2 * nb + i];
    }
    __shared__ double red[3][256];
    red[0][threadIdx.x] = sm;
    red[1][threadIdx.x] = sc;
    red[2][threadIdx.x] = sh;
    __syncthreads();
    for (int s = blockDim.x / 2; s > 0; s >>= 1) {
        if ((int)threadIdx.x < s) {
            red[0][threadIdx.x] += red[0][threadIdx.x + s];
            red[1][threadIdx.x] += red[1][threadIdx.x + s];
            red[2][threadIdx.x] += red[2][threadIdx.x + s];
        }
        __syncthreads();
    }
    if (threadIdx.x == 0) {
        double ms = fmax(red[0][0], 1.0);
        out[0] = (float)(red[1][0] / ms + 2.0 * red[2][0] / ms);
    }
}

// ---------------- host launch ----------------

extern "C" void kernel_launch(void* const* d_in, const int* in_sizes, int n_in,
                              void* d_out, int out_size, void* d_ws, size_t ws_size,
                              hipStream_t stream) {
    const float* pred   = (const float*)d_in[0];
    const float* target = (const float*)d_in[1];
    float* out = (float*)d_out;

    const int H = 1024, W = 1024;  // fixed problem shape (W==1024 required by k1)
    int Bn = in_sizes[0] / (3 * H * W);
    size_t plane = (size_t)Bn * H * W * sizeof(float);

    char* ws = (char*)d_ws;
    float* planeA = (float*)ws;            // edge, then mask0 (in place)
    float* planeB = (float*)(ws + plane);  // dilated
    float* partials = (float*)(ws + 2 * plane);

    int g1 = Bn * (H / K1_NR);                 // 512
    int rs = H / SROWS;                        // 16
    int cbP = (W + 245) / 246;                 // 5
    int cb4 = (W + 251) / 252;                 // 5
    int gP = Bn * cbP * rs;
    int g4 = Bn * cb4 * rs;

    // 1. sobel edge_soft -> planeA (channel-staggered rows)
    k1_edge<<<g1, 256, 0, stream>>>(target, planeA, H, W);
    // 2. 11x11 max-pool -> planeB (dilated)
    pool_kernel<5, true, false><<<gP, 256, 0, stream>>>(planeA, nullptr, planeB, H, W);
    // 3. 11x11 min-pool + relu(closed - edge) -> planeA in place (mask0)
    pool_kernel<5, false, true><<<gP, 256, 0, stream>>>(planeB, planeA, planeA, H, W);
    // 4. 5x5 max-pool + compacted masked loss -> partials
    k4_loss<<<g4, 256, 0, stream>>>(pred, target, planeA, partials, H, W, g4);
    // 5. final reduce + combine
    finalize_kernel<<<1, 256, 0, stream>>>(partials, g4, out);
}